// Round 12
// baseline (246.298 us; speedup 1.0000x reference)
//
#include <hip/hip_runtime.h>

// Problem constants
#define BN   8
#define CC   256
#define HH   64
#define WW   64
#define GG   8
#define CG   32
#define KKK  9
#define OO   256
#define HW   (HH*WW)
#define NPAD 256
#define NOUT 216

// halo'd x_h geometry: pixel (y,x) lives at row y+2, col x+2 of a 68x68 grid
#define XH   68
#define XROW (XH*256)            // halves per pixel-row = 17408
#define XB   (XH*XH*256)         // halves per batch    = 1183744

typedef __attribute__((ext_vector_type(8))) _Float16 half8;
typedef __attribute__((ext_vector_type(4))) _Float16 half4;
typedef __attribute__((ext_vector_type(4))) float f32x4;

union U4H8 { uint4 u; half8 h; };
union U2H4 { uint2 u; half4 h; };

#define LGKM0_BARRIER() do { \
    asm volatile("s_waitcnt lgkmcnt(0)" ::: "memory"); \
    __builtin_amdgcn_s_barrier(); \
    __builtin_amdgcn_sched_barrier(0); \
} while (0)

// ---------------------------------------------------------------------------
// K0a: repack w_out -> wt3 FRAGMENT-LINEAR:
// wt3[((s*16 + ot)*64 + lane)*8 + e], s = g*9+kk, oc = ot*16+(lane&15),
// cg = (lane>>4)*8 + e. Wave B-fragment load = contiguous 1 KB.
// ---------------------------------------------------------------------------
__global__ void repack_w(const float* __restrict__ w_out, _Float16* __restrict__ wt3) {
    int idx = blockIdx.x * 256 + threadIdx.x;
    if (idx >= GG * KKK * CG * OO) return;
    int e    = idx & 7;
    int lane = (idx >> 3) & 63;
    int ot   = (idx >> 9) & 15;
    int s    = idx >> 13;          // 0..71
    int kk = s % 9;
    int g  = s / 9;
    int oc = ot * 16 + (lane & 15);
    int cg = (lane >> 4) * 8 + e;
    wt3[idx] = (_Float16)w_out[oc * 2304 + (g * 32 + cg) * 9 + kk];
}

// ---------------------------------------------------------------------------
// K0b: repack conv weights -> wt_conv FRAGMENT-LINEAR (gs = tap*8 + chunk):
// wt_conv[((gs*16 + ot)*64 + lane)*8 + e]; oc >= 216 zero-padded. bias[224].
// ---------------------------------------------------------------------------
__global__ void repack_conv(const float* __restrict__ w_off, const float* __restrict__ b_off,
                            const float* __restrict__ w_attn, const float* __restrict__ b_attn,
                            _Float16* __restrict__ wt_conv, float* __restrict__ bias_c) {
    int idx = blockIdx.x * 256 + threadIdx.x;
    if (idx >= 9 * NPAD * 256) return;
    int e    = idx & 7;
    int lane = (idx >> 3) & 63;
    int ot   = (idx >> 9) & 15;
    int gs   = idx >> 13;          // 0..71
    int tap = gs >> 3;
    int ch  = (gs & 7) * 32 + (lane >> 4) * 8 + e;
    int n   = ot * 16 + (lane & 15);
    float v = 0.f;
    if (n < 144)      v = w_off[(n * 256 + ch) * 9 + tap];
    else if (n < 216) v = w_attn[((n - 144) * 256 + ch) * 9 + tap];
    wt_conv[idx] = (_Float16)v;
    if (idx < 224) {
        float bv = 0.f;
        if (idx < 144)      bv = b_off[idx];
        else if (idx < 216) bv = b_attn[idx - 144];
        bias_c[idx] = bv;
    }
}

// ---------------------------------------------------------------------------
// K0c: repack x f32 NCHW -> x_h f16 halo-NHWC [b][y+2][x+2][c] (68x68 grid,
// borders pre-zeroed by hipMemsetAsync).
// ---------------------------------------------------------------------------
__global__ __launch_bounds__(256) void repack_x(const float* __restrict__ x,
                                                _Float16* __restrict__ x_h) {
    __shared__ _Float16 T[64][264];
    const int bid = blockIdx.x;
    const int b = bid & 7, h = bid >> 3;
    const int t = threadIdx.x;   // = channel
    const float* src = x + (((long)(b * 256 + t)) << 12) + h * 64;
    #pragma unroll
    for (int i = 0; i < 16; ++i) {
        float4 f = ((const float4*)src)[i];
        T[i * 4 + 0][t] = (_Float16)f.x;
        T[i * 4 + 1][t] = (_Float16)f.y;
        T[i * 4 + 2][t] = (_Float16)f.z;
        T[i * 4 + 3][t] = (_Float16)f.w;
    }
    __syncthreads();
    _Float16* dst = x_h + ((long)(b * XH + h + 2) * XH + 2) * 256;
    #pragma unroll
    for (int it = 0; it < 8; ++it) {
        int idx = it * 256 + t;
        int px = idx >> 5, ch = idx & 31;
        uint4 v = *(const uint4*)&T[px][ch * 8];
        *(uint4*)(dst + px * 256 + ch * 8) = v;
    }
}

// ---------------------------------------------------------------------------
// K1: implicit-GEMM conv via f16 MFMA, split-K, BK=64, M-SPLIT.
// Grid 1024 = (b, h, mh); block = 512 thr = 2 K-groups x 4 N-waves.
// M = 32 px (half row), N = 256 (padded). 18 stages/group, 16 MFMA/wave/stage,
// ONE lgkm-only barrier per stage. A double-buffered [grp][buf][32][72] LDS
// (8 thr/px x uint4), zero-halo x_h; B register-direct (fragment-linear).
// 4 blocks/CU -> 4 independent barrier domains per SIMD.
// ---------------------------------------------------------------------------
__global__ __launch_bounds__(512, 4) void conv_mfma(
    const _Float16* __restrict__ x_h, const _Float16* __restrict__ wt_conv,
    const float* __restrict__ bias_c, float* __restrict__ conv_buf) {
    __shared__ alignas(16) char smem[36864];
    _Float16 (*Ald)[2][32][72] = (_Float16 (*)[2][32][72])smem; // 18,432 B
    float* red = (float*)smem;                                  // epilogue reuse (36,864 B)

    const int bid = blockIdx.x;
    const int b = bid & 7, h = (bid >> 3) & 63, mh = bid >> 9;
    const int t = threadIdx.x;
    const int lane = t & 63;
    const int wv = t >> 6;
    const int group = wv >> 2;      // K-half: gs 0..35 | 36..71
    const int wg = wv & 3;          // N quarter
    const int tl = t & 255;
    const int px2 = tl >> 3, sub = tl & 7;
    const int gs0 = group * 36;

    f32x4 acc[2][4];
    #pragma unroll
    for (int i = 0; i < 2; ++i)
        #pragma unroll
        for (int j = 0; j < 4; ++j) acc[i][j] = (f32x4){0.f, 0.f, 0.f, 0.f};

    const _Float16* xb = x_h + (long)b * XB + sub * 8;
    const _Float16* wB = wt_conv + (long)(wg * 256 + lane) * 8;

    uint4 aR;
    uint4 ba0, ba1, ba2, ba3;   // B even slice (kh=0)
    uint4 bb0, bb1, bb2, bb3;   // B odd slice  (kh=1)

    // ---- prologue: A(0) -> buf0; A(1) -> reg; B(0) pair -> regs ----
    {
        int gs = gs0;
        int tap = gs >> 3, cb = (gs & 7) * 32;
        int y = h + tap / 3 + 1, xc = mh * 32 + px2 + tap % 3 + 1;
        uint4 a0 = *(const uint4*)(xb + ((long)(y * XH + xc)) * 256 + cb);
        *(uint4*)&Ald[group][0][px2][sub * 8] = a0;
    }
    {
        int gs = gs0 + 2;
        int tap = gs >> 3, cb = (gs & 7) * 32;
        int y = h + tap / 3 + 1, xc = mh * 32 + px2 + tap % 3 + 1;
        aR = *(const uint4*)(xb + ((long)(y * XH + xc)) * 256 + cb);
    }
    {
        const _Float16* wa = wB + (long)gs0 * 8192;
        ba0 = *(const uint4*)(wa);
        ba1 = *(const uint4*)(wa + 512);
        ba2 = *(const uint4*)(wa + 1024);
        ba3 = *(const uint4*)(wa + 1536);
        const _Float16* wb_ = wB + (long)(gs0 + 1) * 8192;
        bb0 = *(const uint4*)(wb_);
        bb1 = *(const uint4*)(wb_ + 512);
        bb2 = *(const uint4*)(wb_ + 1024);
        bb3 = *(const uint4*)(wb_ + 1536);
    }
    LGKM0_BARRIER();

    for (int s = 0; s < 18; ++s) {
        // (1) LDS write A(s+1) from prefetched reg (other buffer)
        if (s < 17) {
            *(uint4*)&Ald[group][(s + 1) & 1][px2][sub * 8] = aR;
        }
        // (2) issue A(s+2)
        if (s < 16) {
            int gs = gs0 + 2 * (s + 2);
            int tap = gs >> 3, cb = (gs & 7) * 32;
            int y = h + tap / 3 + 1, xc = mh * 32 + px2 + tap % 3 + 1;
            aR = *(const uint4*)(xb + ((long)(y * XH + xc)) * 256 + cb);
        }
        // (3) MFMA(s): 2 K-halves x 2 M x 4 N
        {
            const int k0 = (lane >> 4) * 8;
            U4H8 b0, b1, b2, b3;
            b0.u = ba0; b1.u = ba1; b2.u = ba2; b3.u = ba3;
            #pragma unroll
            for (int mi = 0; mi < 2; ++mi) {
                half8 a = *(const half8*)&Ald[group][s & 1][mi * 16 + (lane & 15)][k0];
                acc[mi][0] = __builtin_amdgcn_mfma_f32_16x16x32_f16(a, b0.h, acc[mi][0], 0, 0, 0);
                acc[mi][1] = __builtin_amdgcn_mfma_f32_16x16x32_f16(a, b1.h, acc[mi][1], 0, 0, 0);
                acc[mi][2] = __builtin_amdgcn_mfma_f32_16x16x32_f16(a, b2.h, acc[mi][2], 0, 0, 0);
                acc[mi][3] = __builtin_amdgcn_mfma_f32_16x16x32_f16(a, b3.h, acc[mi][3], 0, 0, 0);
            }
            b0.u = bb0; b1.u = bb1; b2.u = bb2; b3.u = bb3;
            #pragma unroll
            for (int mi = 0; mi < 2; ++mi) {
                half8 a = *(const half8*)&Ald[group][s & 1][mi * 16 + (lane & 15)][32 + k0];
                acc[mi][0] = __builtin_amdgcn_mfma_f32_16x16x32_f16(a, b0.h, acc[mi][0], 0, 0, 0);
                acc[mi][1] = __builtin_amdgcn_mfma_f32_16x16x32_f16(a, b1.h, acc[mi][1], 0, 0, 0);
                acc[mi][2] = __builtin_amdgcn_mfma_f32_16x16x32_f16(a, b2.h, acc[mi][2], 0, 0, 0);
                acc[mi][3] = __builtin_amdgcn_mfma_f32_16x16x32_f16(a, b3.h, acc[mi][3], 0, 0, 0);
            }
        }
        // (4) issue B(s+1) pair
        if (s < 17) {
            int gs = gs0 + 2 * (s + 1);
            const _Float16* wa = wB + (long)gs * 8192;
            ba0 = *(const uint4*)(wa);
            ba1 = *(const uint4*)(wa + 512);
            ba2 = *(const uint4*)(wa + 1024);
            ba3 = *(const uint4*)(wa + 1536);
            const _Float16* wb_ = wB + (long)(gs + 1) * 8192;
            bb0 = *(const uint4*)(wb_);
            bb1 = *(const uint4*)(wb_ + 512);
            bb2 = *(const uint4*)(wb_ + 1024);
            bb3 = *(const uint4*)(wb_ + 1536);
        }
        // (5) LDS-visibility barrier only (no vmcnt drain)
        LGKM0_BARRIER();
    }

    // ---- cross-group K reduction via LDS (1 round) ----
    __syncthreads();
    if (group == 1) {
        #pragma unroll
        for (int m2 = 0; m2 < 2; ++m2)
            #pragma unroll
            for (int j = 0; j < 4; ++j)
                *(f32x4*)&red[tl * 36 + m2 * 16 + j * 4] = acc[m2][j];
    }
    __syncthreads();
    if (group == 0) {
        #pragma unroll
        for (int m2 = 0; m2 < 2; ++m2)
            #pragma unroll
            for (int j = 0; j < 4; ++j) {
                f32x4 v = *(const f32x4*)&red[tl * 36 + m2 * 16 + j * 4];
                acc[m2][j] += v;
            }
    }

    // ---- epilogue (group 0 stores) ----
    if (group == 0) {
        const int colb = (lane >> 4) * 4;
        #pragma unroll
        for (int mi = 0; mi < 2; ++mi) {
            int px0 = mh * 32 + mi * 16 + colb;
            #pragma unroll
            for (int j = 0; j < 4; ++j) {
                int oc = wg * 64 + j * 16 + (lane & 15);
                if (oc < NOUT) {
                    float bb = bias_c[oc];
                    float4 v = make_float4(acc[mi][j][0] + bb, acc[mi][j][1] + bb,
                                           acc[mi][j][2] + bb, acc[mi][j][3] + bb);
                    *(float4*)&conv_buf[((long)b * NOUT + oc) * HW + h * WW + px0] = v;
                }
            }
        }
    }
}

// ---------------------------------------------------------------------------
// coords on the zero-halo grid: NO masks, NO per-corner selects.
// ---------------------------------------------------------------------------
__device__ __forceinline__ void calc_coords(int h, int px, int ki, int kj,
    float dy, float dx, int& i00,
    float& u00, float& u01, float& u10, float& u11) {
    float py  = (float)(h - 1 + ki) + dy;
    float pxf = (float)(px - 1 + kj) + dx;
    float y0f = floorf(py), x0f = floorf(pxf);
    float wy1 = py - y0f, wx1 = pxf - x0f;
    float wy0 = 1.f - wy1, wx0 = 1.f - wx1;
    int y0 = min(max((int)y0f, -2), 64);
    int x0 = min(max((int)x0f, -2), 64);
    u00 = wy0 * wx0; u01 = wy0 * wx1;
    u10 = wy1 * wx0; u11 = wy1 * wx1;
    i00 = (y0 + 2) * XH + (x0 + 2);
}

// ---------------------------------------------------------------------------
// K3: fused softmax + bilinear sampling + modulation + MFMA contraction.
// Split-K, BK=32, M-SPLIT: grid 1024 = (b, h, mh); 512 thr; M = 32 px.
// Gather/blend: 8 thr/px, uint2 per corner (4-half channel slice).
// 36 stages, 8 MFMA/wave/stage, one lgkm-only barrier per stage.
// 4 blocks/CU -> 4 independent barrier domains per SIMD.
// ---------------------------------------------------------------------------
__global__ __launch_bounds__(512, 4) void sample_gemm_mfma(
    const _Float16* __restrict__ x_h, const float* __restrict__ conv_buf,
    const _Float16* __restrict__ wt3,
    const float* __restrict__ b_out, float* __restrict__ out) {
    __shared__ alignas(16) char smem[36864];
    _Float16 (*Ald)[2][32][40] = (_Float16 (*)[2][32][40])smem; // 10,240 B
    float* attnL = (float*)(smem + 10240);                      // 72*32 f32 = 9,216 B
    float* red = (float*)smem;                                  // epilogue reuse (36,864 B)

    const int bid = blockIdx.x;
    const int b = bid & 7, h = (bid >> 3) & 63, mh = bid >> 9;
    const int t = threadIdx.x;
    const int lane = t & 63;
    const int wv = t >> 6;
    const int group = wv >> 2;      // K-half
    const int wg = wv & 3;          // N quarter
    const int tl = t & 255;
    const int px2 = tl >> 3, sub = tl & 7;
    const int pxg = mh * 32 + px2;  // global pixel x
    const int gs0 = group * 36;

    f32x4 acc[2][4];
    #pragma unroll
    for (int i = 0; i < 2; ++i)
        #pragma unroll
        for (int j = 0; j < 4; ++j) acc[i][j] = (f32x4){0.f, 0.f, 0.f, 0.f};

    // cbase points at (b, :, h, mh*32)
    const float* cbase = conv_buf + (long)b * NOUT * HW + h * WW + mh * 32;
    const _Float16* xbase = x_h + (long)b * XB + sub * 4;
    const _Float16* wB3 = wt3 + (long)(wg * 256 + lane) * 8;

    // ---- preamble 1: softmax over 9 taps; 256 threads = (g 0..7, px 0..31) ----
    if (t < 256) {
        int ppx = t & 31, g = t >> 5;
        const float* ap = cbase + (long)(144 + g * 9) * HW + ppx;
        float v[9];
        float m = -1e30f;
        #pragma unroll
        for (int k = 0; k < 9; ++k) { v[k] = ap[k * HW]; m = fmaxf(m, v[k]); }
        float ssum = 0.f;
        #pragma unroll
        for (int k = 0; k < 9; ++k) { v[k] = __expf(v[k] - m); ssum += v[k]; }
        float inv = 1.f / ssum;
        #pragma unroll
        for (int k = 0; k < 9; ++k) attnL[(g * 9 + k) * 32 + ppx] = v[k] * inv;
    }
    float dy0 = cbase[(2 * gs0) * HW + px2], dx0 = cbase[(2 * gs0 + 1) * HW + px2];
    __syncthreads();   // attnL ready

    // ---- preamble 2: blend A(0) -> buf0; gathers(1); d(2); B(0) ----
    uint2 q00, q01, q10, q11;
    float u00, u01, u10, u11;
    float dyN, dxN;
    uint4 bq0, bq1, bq2, bq3;
    {
        int i00; float v00, v01, v10, v11;
        calc_coords(h, pxg, 0, 0, dy0, dx0, i00, v00, v01, v10, v11);
        const _Float16* xg = xbase + (group * 4) * 32 + (long)i00 * 256;
        uint2 a00 = *(const uint2*)(xg);
        uint2 a01 = *(const uint2*)(xg + 256);
        uint2 a10 = *(const uint2*)(xg + XROW);
        uint2 a11 = *(const uint2*)(xg + XROW + 256);
        float av = attnL[gs0 * 32 + px2];
        U2H4 h00, h01, h10, h11;
        h00.u = a00; h01.u = a01; h10.u = a10; h11.u = a11;
        half4 rr = h00.h * (_Float16)v00 + h01.h * (_Float16)v01
                 + h10.h * (_Float16)v10 + h11.h * (_Float16)v11;
        rr = rr * (_Float16)av;
        U2H4 w; w.h = rr;
        *(uint2*)&Ald[group][0][px2][sub * 4] = w.u;
    }
    {
        // gathers for stage 1 (kk=1, same g)
        float dy1 = cbase[(2 * (gs0 + 1)) * HW + px2];
        float dx1 = cbase[(2 * (gs0 + 1) + 1) * HW + px2];
        int i00;
        calc_coords(h, pxg, 0, 1, dy1, dx1, i00, u00, u01, u10, u11);
        const _Float16* xg = xbase + (group * 4) * 32 + (long)i00 * 256;
        q00 = *(const uint2*)(xg);
        q01 = *(const uint2*)(xg + 256);
        q10 = *(const uint2*)(xg + XROW);
        q11 = *(const uint2*)(xg + XROW + 256);
        dyN = cbase[(2 * (gs0 + 2)) * HW + px2];
        dxN = cbase[(2 * (gs0 + 2) + 1) * HW + px2];
    }
    {
        const _Float16* wsB = wB3 + (long)gs0 * 8192;
        bq0 = *(const uint4*)(wsB);
        bq1 = *(const uint4*)(wsB + 512);
        bq2 = *(const uint4*)(wsB + 1024);
        bq3 = *(const uint4*)(wsB + 1536);
    }
    LGKM0_BARRIER();

    for (int s = 0; s < 36; ++s) {
        const int gs = gs0 + s;
        // (1) blend A(s+1) from prefetched gathers; LDS write (other buffer)
        if (s < 35) {
            float av = attnL[(gs + 1) * 32 + px2];
            U2H4 a00, a01, a10, a11;
            a00.u = q00; a01.u = q01; a10.u = q10; a11.u = q11;
            half4 rr = a00.h * (_Float16)u00 + a01.h * (_Float16)u01
                     + a10.h * (_Float16)u10 + a11.h * (_Float16)u11;
            rr = rr * (_Float16)av;
            U2H4 w; w.h = rr;
            *(uint2*)&Ald[group][(s + 1) & 1][px2][sub * 4] = w.u;
        }
        // (2) coords(s+2) + issue gathers(s+2) + d(s+3)
        if (s < 34) {
            int sn = s + 2;
            int g = group * 4 + sn / 9, kk = sn % 9;
            int i00;
            calc_coords(h, pxg, kk / 3, kk % 3, dyN, dxN, i00, u00, u01, u10, u11);
            const _Float16* xg = xbase + g * 32 + (long)i00 * 256;
            q00 = *(const uint2*)(xg);
            q01 = *(const uint2*)(xg + 256);
            q10 = *(const uint2*)(xg + XROW);
            q11 = *(const uint2*)(xg + XROW + 256);
            int s3 = min(s + 3, 35);
            dyN = cbase[(2 * (gs0 + s3)) * HW + px2];
            dxN = cbase[(2 * (gs0 + s3) + 1) * HW + px2];
        }
        // (3) MFMA(s): 2 M x 4 N
        {
            const int k0 = (lane >> 4) * 8;
            U4H8 b0, b1, b2, b3; b0.u = bq0; b1.u = bq1; b2.u = bq2; b3.u = bq3;
            #pragma unroll
            for (int mi = 0; mi < 2; ++mi) {
                half8 a = *(const half8*)&Ald[group][s & 1][mi * 16 + (lane & 15)][k0];
                acc[mi][0] = __builtin_amdgcn_mfma_f32_16x16x32_f16(a, b0.h, acc[mi][0], 0, 0, 0);
                acc[mi][1] = __builtin_amdgcn_mfma_f32_16x16x32_f16(a, b1.h, acc[mi][1], 0, 0, 0);
                acc[mi][2] = __builtin_amdgcn_mfma_f32_16x16x32_f16(a, b2.h, acc[mi][2], 0, 0, 0);
                acc[mi][3] = __builtin_amdgcn_mfma_f32_16x16x32_f16(a, b3.h, acc[mi][3], 0, 0, 0);
            }
        }
        // (4) issue B(s+1)
        if (s < 35) {
            const _Float16* wsB = wB3 + (long)(gs + 1) * 8192;
            bq0 = *(const uint4*)(wsB);
            bq1 = *(const uint4*)(wsB + 512);
            bq2 = *(const uint4*)(wsB + 1024);
            bq3 = *(const uint4*)(wsB + 1536);
        }
        // (5) LDS-visibility barrier only
        LGKM0_BARRIER();
    }

    // ---- cross-group K reduction via LDS (1 round) ----
    __syncthreads();
    if (group == 1) {
        #pragma unroll
        for (int m2 = 0; m2 < 2; ++m2)
            #pragma unroll
            for (int j = 0; j < 4; ++j)
                *(f32x4*)&red[tl * 36 + m2 * 16 + j * 4] = acc[m2][j];
    }
    __syncthreads();
    if (group == 0) {
        #pragma unroll
        for (int m2 = 0; m2 < 2; ++m2)
            #pragma unroll
            for (int j = 0; j < 4; ++j) {
                f32x4 v = *(const f32x4*)&red[tl * 36 + m2 * 16 + j * 4];
                acc[m2][j] += v;
            }
    }

    // ---- epilogue (group 0 stores) ----
    if (group == 0) {
        const int colb = (lane >> 4) * 4;
        #pragma unroll
        for (int mi = 0; mi < 2; ++mi) {
            int px0 = mh * 32 + mi * 16 + colb;
            #pragma unroll
            for (int j = 0; j < 4; ++j) {
                int oc = wg * 64 + j * 16 + (lane & 15);
                float bb = b_out[oc];
                float4 v = make_float4(acc[mi][j][0] + bb, acc[mi][j][1] + bb,
                                       acc[mi][j][2] + bb, acc[mi][j][3] + bb);
                *(float4*)&out[((long)b * OO + oc) * HW + h * WW + px0] = v;
            }
        }
    }
}

// ---------------------------------------------------------------------------
extern "C" void kernel_launch(void* const* d_in, const int* in_sizes, int n_in,
                              void* d_out, int out_size, void* d_ws, size_t ws_size,
                              hipStream_t stream) {
    const float* x      = (const float*)d_in[0];
    const float* w_off  = (const float*)d_in[1];
    const float* b_off  = (const float*)d_in[2];
    const float* w_attn = (const float*)d_in[3];
    const float* b_attn = (const float*)d_in[4];
    const float* w_out  = (const float*)d_in[5];
    const float* b_out  = (const float*)d_in[6];
    float* out = (float*)d_out;

    _Float16* x_h     = (_Float16*)d_ws;                    // 8*68*68*256 = 9,469,952 halves
    float* conv_buf   = (float*)(x_h + 9469952);            // 7,077,888 floats
    _Float16* wt3     = (_Float16*)(conv_buf + 7077888);    // 589,824 halves
    _Float16* wt_conv = wt3 + 589824;                       // 589,824 halves
    float* bias_c     = (float*)(wt_conv + 589824);         // 224 floats

    // zero the halo'd x_h once; repack writes the interior
    hipMemsetAsync(x_h, 0, (size_t)9469952 * sizeof(_Float16), stream);

    repack_w<<<dim3((589824 + 255) / 256), dim3(256), 0, stream>>>(w_out, wt3);
    repack_conv<<<dim3((9 * NPAD * 256 + 255) / 256), dim3(256), 0, stream>>>(
        w_off, b_off, w_attn, b_attn, wt_conv, bias_c);
    repack_x<<<dim3(512), dim3(256), 0, stream>>>(x, x_h);

    conv_mfma<<<dim3(1024), dim3(512), 0, stream>>>(x_h, wt_conv, bias_c, conv_buf);

    sample_gemm_mfma<<<dim3(1024), dim3(512), 0, stream>>>(
        x_h, conv_buf, wt3, b_out, out);
}

// Round 13
// 215.051 us; speedup vs baseline: 1.1453x; 1.1453x over previous
//
#include <hip/hip_runtime.h>

// Problem constants
#define BN   8
#define CC   256
#define HH   64
#define WW   64
#define GG   8
#define CG   32
#define KKK  9
#define OO   256
#define HW   (HH*WW)
#define NPAD 256
#define NOUT 216

// halo'd x_h geometry: pixel (y,x) lives at row y+2, col x+2 of a 68x68 grid
#define XH   68
#define XROW (XH*256)            // halves per pixel-row = 17408
#define XB   (XH*XH*256)         // halves per batch    = 1183744

typedef __attribute__((ext_vector_type(8))) _Float16 half8;
typedef __attribute__((ext_vector_type(4))) float f32x4;

union U4H8 { uint4 u; half8 h; };

#define LGKM0_BARRIER() do { \
    asm volatile("s_waitcnt lgkmcnt(0)" ::: "memory"); \
    __builtin_amdgcn_s_barrier(); \
    __builtin_amdgcn_sched_barrier(0); \
} while (0)

// ---------------------------------------------------------------------------
// K0a: repack w_out -> wt3 FRAGMENT-LINEAR:
// wt3[((s*16 + ot)*64 + lane)*8 + e], s = g*9+kk, oc = ot*16+(lane&15),
// cg = (lane>>4)*8 + e. Wave B-fragment load = contiguous 1 KB.
// ---------------------------------------------------------------------------
__global__ void repack_w(const float* __restrict__ w_out, _Float16* __restrict__ wt3) {
    int idx = blockIdx.x * 256 + threadIdx.x;
    if (idx >= GG * KKK * CG * OO) return;
    int e    = idx & 7;
    int lane = (idx >> 3) & 63;
    int ot   = (idx >> 9) & 15;
    int s    = idx >> 13;          // 0..71
    int kk = s % 9;
    int g  = s / 9;
    int oc = ot * 16 + (lane & 15);
    int cg = (lane >> 4) * 8 + e;
    wt3[idx] = (_Float16)w_out[oc * 2304 + (g * 32 + cg) * 9 + kk];
}

// ---------------------------------------------------------------------------
// K0b: repack conv weights -> wt_conv FRAGMENT-LINEAR (gs = tap*8 + chunk):
// wt_conv[((gs*16 + ot)*64 + lane)*8 + e]; oc >= 216 zero-padded. bias[224].
// ---------------------------------------------------------------------------
__global__ void repack_conv(const float* __restrict__ w_off, const float* __restrict__ b_off,
                            const float* __restrict__ w_attn, const float* __restrict__ b_attn,
                            _Float16* __restrict__ wt_conv, float* __restrict__ bias_c) {
    int idx = blockIdx.x * 256 + threadIdx.x;
    if (idx >= 9 * NPAD * 256) return;
    int e    = idx & 7;
    int lane = (idx >> 3) & 63;
    int ot   = (idx >> 9) & 15;
    int gs   = idx >> 13;          // 0..71
    int tap = gs >> 3;
    int ch  = (gs & 7) * 32 + (lane >> 4) * 8 + e;
    int n   = ot * 16 + (lane & 15);
    float v = 0.f;
    if (n < 144)      v = w_off[(n * 256 + ch) * 9 + tap];
    else if (n < 216) v = w_attn[((n - 144) * 256 + ch) * 9 + tap];
    wt_conv[idx] = (_Float16)v;
    if (idx < 224) {
        float bv = 0.f;
        if (idx < 144)      bv = b_off[idx];
        else if (idx < 216) bv = b_attn[idx - 144];
        bias_c[idx] = bv;
    }
}

// ---------------------------------------------------------------------------
// K0c: repack x f32 NCHW -> x_h f16 halo-NHWC [b][y+2][x+2][c] (68x68 grid,
// borders pre-zeroed by hipMemsetAsync).
// ---------------------------------------------------------------------------
__global__ __launch_bounds__(256) void repack_x(const float* __restrict__ x,
                                                _Float16* __restrict__ x_h) {
    __shared__ _Float16 T[64][264];
    const int bid = blockIdx.x;
    const int b = bid & 7, h = bid >> 3;
    const int t = threadIdx.x;   // = channel
    const float* src = x + (((long)(b * 256 + t)) << 12) + h * 64;
    #pragma unroll
    for (int i = 0; i < 16; ++i) {
        float4 f = ((const float4*)src)[i];
        T[i * 4 + 0][t] = (_Float16)f.x;
        T[i * 4 + 1][t] = (_Float16)f.y;
        T[i * 4 + 2][t] = (_Float16)f.z;
        T[i * 4 + 3][t] = (_Float16)f.w;
    }
    __syncthreads();
    _Float16* dst = x_h + ((long)(b * XH + h + 2) * XH + 2) * 256;
    #pragma unroll
    for (int it = 0; it < 8; ++it) {
        int idx = it * 256 + t;
        int px = idx >> 5, ch = idx & 31;
        uint4 v = *(const uint4*)&T[px][ch * 8];
        *(uint4*)(dst + px * 256 + ch * 8) = v;
    }
}

// ---------------------------------------------------------------------------
// K1: implicit-GEMM conv via f16 MFMA, split-K, BK=64 (2 chunks per stage).
// Block = 512 thr (8 waves) = 2 K-groups x 4 N-waves. M=64 px, N=256 (padded).
// Grid 512 = (b,h). 18 stages/group, 32 MFMA/wave/stage, ONE lgkm-only
// barrier per stage. (R10 kernel, verified.)
// ---------------------------------------------------------------------------
__global__ __launch_bounds__(512, 4) void conv_mfma(
    const _Float16* __restrict__ x_h, const _Float16* __restrict__ wt_conv,
    const float* __restrict__ bias_c, float* __restrict__ conv_buf) {
    __shared__ alignas(16) char smem[36864];
    _Float16 (*Ald)[2][64][72] = (_Float16 (*)[2][64][72])smem; // 36,864 B
    float* red = (float*)smem;                                  // epilogue reuse

    const int bid = blockIdx.x;
    const int b = bid & 7, h = bid >> 3;
    const int t = threadIdx.x;
    const int lane = t & 63;
    const int wv = t >> 6;
    const int group = wv >> 2;      // K-half: gs 0..35 | 36..71
    const int wg = wv & 3;          // N quarter
    const int tl = t & 255;
    const int px = tl >> 2, cq = tl & 3;
    const int gs0 = group * 36;

    f32x4 acc[4][4];
    #pragma unroll
    for (int i = 0; i < 4; ++i)
        #pragma unroll
        for (int j = 0; j < 4; ++j) acc[i][j] = (f32x4){0.f, 0.f, 0.f, 0.f};

    const _Float16* xb = x_h + (long)b * XB + cq * 8;
    const _Float16* wB = wt_conv + (long)(wg * 256 + lane) * 8;

    uint4 aR0, aR1;
    uint4 ba0, ba1, ba2, ba3;   // B even slice (kh=0)
    uint4 bb0, bb1, bb2, bb3;   // B odd slice  (kh=1)

    // ---- prologue: A(0) -> buf0; A(1) -> regs; B(0) pair -> regs ----
    {
        int gs = gs0;
        int tap = gs >> 3, cb = (gs & 7) * 32;
        int y = h + tap / 3 + 1, xc = px + tap % 3 + 1;
        const _Float16* p = xb + ((long)(y * XH + xc)) * 256 + cb;
        uint4 a0 = *(const uint4*)(p);
        uint4 a1 = *(const uint4*)(p + 32);
        *(uint4*)&Ald[group][0][px][cq * 8] = a0;
        *(uint4*)&Ald[group][0][px][32 + cq * 8] = a1;
    }
    {
        int gs = gs0 + 2;
        int tap = gs >> 3, cb = (gs & 7) * 32;
        int y = h + tap / 3 + 1, xc = px + tap % 3 + 1;
        const _Float16* p = xb + ((long)(y * XH + xc)) * 256 + cb;
        aR0 = *(const uint4*)(p);
        aR1 = *(const uint4*)(p + 32);
    }
    {
        const _Float16* wa = wB + (long)gs0 * 8192;
        ba0 = *(const uint4*)(wa);
        ba1 = *(const uint4*)(wa + 512);
        ba2 = *(const uint4*)(wa + 1024);
        ba3 = *(const uint4*)(wa + 1536);
        const _Float16* wb_ = wB + (long)(gs0 + 1) * 8192;
        bb0 = *(const uint4*)(wb_);
        bb1 = *(const uint4*)(wb_ + 512);
        bb2 = *(const uint4*)(wb_ + 1024);
        bb3 = *(const uint4*)(wb_ + 1536);
    }
    LGKM0_BARRIER();

    for (int s = 0; s < 18; ++s) {
        // (1) LDS write A(s+1) from prefetched regs (other buffer)
        if (s < 17) {
            *(uint4*)&Ald[group][(s + 1) & 1][px][cq * 8] = aR0;
            *(uint4*)&Ald[group][(s + 1) & 1][px][32 + cq * 8] = aR1;
        }
        // (2) issue A(s+2)
        if (s < 16) {
            int gs = gs0 + 2 * (s + 2);
            int tap = gs >> 3, cb = (gs & 7) * 32;
            int y = h + tap / 3 + 1, xc = px + tap % 3 + 1;
            const _Float16* p = xb + ((long)(y * XH + xc)) * 256 + cb;
            aR0 = *(const uint4*)(p);
            aR1 = *(const uint4*)(p + 32);
        }
        // (3) MFMA(s): 2 K-halves x 4 M x 4 N from LDS buf[s&1]
        {
            const int k0 = (lane >> 4) * 8;
            U4H8 b0, b1, b2, b3;
            b0.u = ba0; b1.u = ba1; b2.u = ba2; b3.u = ba3;
            #pragma unroll
            for (int mi = 0; mi < 4; ++mi) {
                half8 a = *(const half8*)&Ald[group][s & 1][mi * 16 + (lane & 15)][k0];
                acc[mi][0] = __builtin_amdgcn_mfma_f32_16x16x32_f16(a, b0.h, acc[mi][0], 0, 0, 0);
                acc[mi][1] = __builtin_amdgcn_mfma_f32_16x16x32_f16(a, b1.h, acc[mi][1], 0, 0, 0);
                acc[mi][2] = __builtin_amdgcn_mfma_f32_16x16x32_f16(a, b2.h, acc[mi][2], 0, 0, 0);
                acc[mi][3] = __builtin_amdgcn_mfma_f32_16x16x32_f16(a, b3.h, acc[mi][3], 0, 0, 0);
            }
            b0.u = bb0; b1.u = bb1; b2.u = bb2; b3.u = bb3;
            #pragma unroll
            for (int mi = 0; mi < 4; ++mi) {
                half8 a = *(const half8*)&Ald[group][s & 1][mi * 16 + (lane & 15)][32 + k0];
                acc[mi][0] = __builtin_amdgcn_mfma_f32_16x16x32_f16(a, b0.h, acc[mi][0], 0, 0, 0);
                acc[mi][1] = __builtin_amdgcn_mfma_f32_16x16x32_f16(a, b1.h, acc[mi][1], 0, 0, 0);
                acc[mi][2] = __builtin_amdgcn_mfma_f32_16x16x32_f16(a, b2.h, acc[mi][2], 0, 0, 0);
                acc[mi][3] = __builtin_amdgcn_mfma_f32_16x16x32_f16(a, b3.h, acc[mi][3], 0, 0, 0);
            }
        }
        // (4) issue B(s+1) pair
        if (s < 17) {
            int gs = gs0 + 2 * (s + 1);
            const _Float16* wa = wB + (long)gs * 8192;
            ba0 = *(const uint4*)(wa);
            ba1 = *(const uint4*)(wa + 512);
            ba2 = *(const uint4*)(wa + 1024);
            ba3 = *(const uint4*)(wa + 1536);
            const _Float16* wb_ = wB + (long)(gs + 1) * 8192;
            bb0 = *(const uint4*)(wb_);
            bb1 = *(const uint4*)(wb_ + 512);
            bb2 = *(const uint4*)(wb_ + 1024);
            bb3 = *(const uint4*)(wb_ + 1536);
        }
        // (5) LDS-visibility barrier only (no vmcnt drain)
        LGKM0_BARRIER();
    }

    // ---- cross-group K reduction via LDS (2 rounds) ----
    #pragma unroll
    for (int r = 0; r < 2; ++r) {
        __syncthreads();
        if (group == 1) {
            #pragma unroll
            for (int m2 = 0; m2 < 2; ++m2)
                #pragma unroll
                for (int j = 0; j < 4; ++j)
                    *(f32x4*)&red[tl * 36 + m2 * 16 + j * 4] = acc[r * 2 + m2][j];
        }
        __syncthreads();
        if (group == 0) {
            #pragma unroll
            for (int m2 = 0; m2 < 2; ++m2)
                #pragma unroll
                for (int j = 0; j < 4; ++j) {
                    f32x4 v = *(const f32x4*)&red[tl * 36 + m2 * 16 + j * 4];
                    acc[r * 2 + m2][j] += v;
                }
        }
    }

    // ---- epilogue (group 0 stores) ----
    if (group == 0) {
        const int colb = (lane >> 4) * 4;
        #pragma unroll
        for (int mi = 0; mi < 4; ++mi) {
            int px0 = mi * 16 + colb;
            #pragma unroll
            for (int j = 0; j < 4; ++j) {
                int oc = wg * 64 + j * 16 + (lane & 15);
                if (oc < NOUT) {
                    float bb = bias_c[oc];
                    float4 v = make_float4(acc[mi][j][0] + bb, acc[mi][j][1] + bb,
                                           acc[mi][j][2] + bb, acc[mi][j][3] + bb);
                    *(float4*)&conv_buf[((long)b * NOUT + oc) * HW + h * WW + px0] = v;
                }
            }
        }
    }
}

// ---------------------------------------------------------------------------
// coords on the zero-halo grid: NO masks, NO per-corner selects.
// ---------------------------------------------------------------------------
__device__ __forceinline__ void calc_coords(int h, int px, int ki, int kj,
    float dy, float dx, int& i00,
    float& u00, float& u01, float& u10, float& u11) {
    float py  = (float)(h - 1 + ki) + dy;
    float pxf = (float)(px - 1 + kj) + dx;
    float y0f = floorf(py), x0f = floorf(pxf);
    float wy1 = py - y0f, wx1 = pxf - x0f;
    float wy0 = 1.f - wy1, wx0 = 1.f - wx1;
    int y0 = min(max((int)y0f, -2), 64);
    int x0 = min(max((int)x0f, -2), 64);
    u00 = wy0 * wx0; u01 = wy0 * wx1;
    u10 = wy1 * wx0; u11 = wy1 * wx1;
    i00 = (y0 + 2) * XH + (x0 + 2);
}

// ---------------------------------------------------------------------------
// K3: fused softmax + bilinear sampling + modulation + MFMA contraction.
// Split-K, BK=64 (2 (g,kk) taps per stage), 18 stages, 32 MFMA/wave/stage,
// one lgkm-only barrier per stage. R9 kernel (refcheck-proven) with
// __launch_bounds__(512, 2): grid 512 caps residency at 2 blocks/CU anyway,
// so the 256-VGPR budget removes R9's spill without losing occupancy.
// ---------------------------------------------------------------------------
__global__ __launch_bounds__(512, 2) void sample_gemm_mfma(
    const _Float16* __restrict__ x_h, const float* __restrict__ conv_buf,
    const _Float16* __restrict__ wt3,
    const float* __restrict__ b_out, float* __restrict__ out) {
    __shared__ alignas(16) char smem[55296];
    _Float16 (*Ald)[2][64][72] = (_Float16 (*)[2][64][72])smem; // 36,864 B
    float* attnL = (float*)(smem + 36864);                      // 18,432 B
    float* red = (float*)smem;                                  // epilogue reuse

    const int bid = blockIdx.x;
    const int b = bid & 7, h = bid >> 3;
    const int t = threadIdx.x;
    const int lane = t & 63;
    const int wv = t >> 6;
    const int group = wv >> 2;      // K-half
    const int wg = wv & 3;          // N quarter
    const int tl = t & 255;
    const int px = tl >> 2, cq = tl & 3;
    const int gs0 = group * 36;

    f32x4 acc[4][4];
    #pragma unroll
    for (int i = 0; i < 4; ++i)
        #pragma unroll
        for (int j = 0; j < 4; ++j) acc[i][j] = (f32x4){0.f, 0.f, 0.f, 0.f};

    const float* cbase = conv_buf + (long)b * NOUT * HW + h * WW;
    const _Float16* xbase = x_h + (long)b * XB + cq * 8;
    const _Float16* wB3 = wt3 + (long)(wg * 256 + lane) * 8;

    // ---- preamble 1: softmax over 9 taps; 512 threads cover (g, px) ----
    {
        int ppx = t & 63, g = t >> 6;
        const float* ap = cbase + (long)(144 + g * 9) * HW + ppx;
        float v[9];
        float m = -1e30f;
        #pragma unroll
        for (int k = 0; k < 9; ++k) { v[k] = ap[k * HW]; m = fmaxf(m, v[k]); }
        float ssum = 0.f;
        #pragma unroll
        for (int k = 0; k < 9; ++k) { v[k] = __expf(v[k] - m); ssum += v[k]; }
        float inv = 1.f / ssum;
        #pragma unroll
        for (int k = 0; k < 9; ++k) attnL[(g * 9 + k) * 64 + ppx] = v[k] * inv;
    }
    // d for stage-0 taps (gs0, gs0+1)
    float dyA0 = cbase[(2 * gs0) * HW + px],     dxA0 = cbase[(2 * gs0 + 1) * HW + px];
    float dyB0 = cbase[(2 * gs0 + 2) * HW + px], dxB0 = cbase[(2 * gs0 + 3) * HW + px];
    __syncthreads();   // attnL ready

    // ---- preamble 2: blend A(0) -> buf0; gathers(1); d(2); B(0) pair ----
    uint4 qa0, qa1, qa2, qa3;   // gathers for even tap of next stage
    uint4 qb0, qb1, qb2, qb3;   // gathers for odd tap
    float uA00, uA01, uA10, uA11, uB00, uB01, uB10, uB11;
    float dyA, dxA, dyB, dxB;
    uint4 ba0, ba1, ba2, ba3, bb0, bb1, bb2, bb3;
    {
        // stage 0, even tap gs0 (kk = gs0 % 9 = 0)
        int i00; float v00, v01, v10, v11;
        calc_coords(h, px, 0, 0, dyA0, dxA0, i00, v00, v01, v10, v11);
        const _Float16* xg = xbase + (gs0 / 9) * 32 + (long)i00 * 256;
        uint4 a00 = *(const uint4*)(xg);
        uint4 a01 = *(const uint4*)(xg + 256);
        uint4 a10 = *(const uint4*)(xg + XROW);
        uint4 a11 = *(const uint4*)(xg + XROW + 256);
        float av = attnL[gs0 * 64 + px];
        U4H8 h00, h01, h10, h11;
        h00.u = a00; h01.u = a01; h10.u = a10; h11.u = a11;
        half8 rr = h00.h * (_Float16)v00 + h01.h * (_Float16)v01
                 + h10.h * (_Float16)v10 + h11.h * (_Float16)v11;
        rr = rr * (_Float16)av;
        *(half8*)&Ald[group][0][px][cq * 8] = rr;
    }
    {
        // stage 0, odd tap gs0+1 (kk = 1)
        int i00; float v00, v01, v10, v11;
        calc_coords(h, px, 0, 1, dyB0, dxB0, i00, v00, v01, v10, v11);
        const _Float16* xg = xbase + ((gs0 + 1) / 9) * 32 + (long)i00 * 256;
        uint4 a00 = *(const uint4*)(xg);
        uint4 a01 = *(const uint4*)(xg + 256);
        uint4 a10 = *(const uint4*)(xg + XROW);
        uint4 a11 = *(const uint4*)(xg + XROW + 256);
        float av = attnL[(gs0 + 1) * 64 + px];
        U4H8 h00, h01, h10, h11;
        h00.u = a00; h01.u = a01; h10.u = a10; h11.u = a11;
        half8 rr = h00.h * (_Float16)v00 + h01.h * (_Float16)v01
                 + h10.h * (_Float16)v10 + h11.h * (_Float16)v11;
        rr = rr * (_Float16)av;
        *(half8*)&Ald[group][0][px][32 + cq * 8] = rr;
    }
    {
        // gathers for stage 1 taps (gs0+2, gs0+3)
        int tA = gs0 + 2, tB = gs0 + 3;
        float dya = cbase[(2 * tA) * HW + px], dxa = cbase[(2 * tA + 1) * HW + px];
        float dyb = cbase[(2 * tB) * HW + px], dxb = cbase[(2 * tB + 1) * HW + px];
        int i00;
        calc_coords(h, px, (tA % 9) / 3, (tA % 9) % 3, dya, dxa, i00, uA00, uA01, uA10, uA11);
        const _Float16* xga = xbase + (tA / 9) * 32 + (long)i00 * 256;
        qa0 = *(const uint4*)(xga);
        qa1 = *(const uint4*)(xga + 256);
        qa2 = *(const uint4*)(xga + XROW);
        qa3 = *(const uint4*)(xga + XROW + 256);
        calc_coords(h, px, (tB % 9) / 3, (tB % 9) % 3, dyb, dxb, i00, uB00, uB01, uB10, uB11);
        const _Float16* xgb = xbase + (tB / 9) * 32 + (long)i00 * 256;
        qb0 = *(const uint4*)(xgb);
        qb1 = *(const uint4*)(xgb + 256);
        qb2 = *(const uint4*)(xgb + XROW);
        qb3 = *(const uint4*)(xgb + XROW + 256);
        // d for stage 2 taps (gs0+4, gs0+5)
        dyA = cbase[(2 * (gs0 + 4)) * HW + px]; dxA = cbase[(2 * (gs0 + 4) + 1) * HW + px];
        dyB = cbase[(2 * (gs0 + 5)) * HW + px]; dxB = cbase[(2 * (gs0 + 5) + 1) * HW + px];
    }
    {
        const _Float16* wa = wB3 + (long)gs0 * 8192;
        ba0 = *(const uint4*)(wa);
        ba1 = *(const uint4*)(wa + 512);
        ba2 = *(const uint4*)(wa + 1024);
        ba3 = *(const uint4*)(wa + 1536);
        const _Float16* wb_ = wB3 + (long)(gs0 + 1) * 8192;
        bb0 = *(const uint4*)(wb_);
        bb1 = *(const uint4*)(wb_ + 512);
        bb2 = *(const uint4*)(wb_ + 1024);
        bb3 = *(const uint4*)(wb_ + 1536);
    }
    LGKM0_BARRIER();

    for (int s = 0; s < 18; ++s) {
        // (1) blend A(s+1) from prefetched gathers; LDS write (other buffer)
        if (s < 17) {
            int tA = gs0 + 2 * (s + 1), tB = tA + 1;
            float avA = attnL[tA * 64 + px];
            float avB = attnL[tB * 64 + px];
            U4H8 a00, a01, a10, a11;
            a00.u = qa0; a01.u = qa1; a10.u = qa2; a11.u = qa3;
            half8 rrA = a00.h * (_Float16)uA00 + a01.h * (_Float16)uA01
                      + a10.h * (_Float16)uA10 + a11.h * (_Float16)uA11;
            rrA = rrA * (_Float16)avA;
            *(half8*)&Ald[group][(s + 1) & 1][px][cq * 8] = rrA;
            a00.u = qb0; a01.u = qb1; a10.u = qb2; a11.u = qb3;
            half8 rrB = a00.h * (_Float16)uB00 + a01.h * (_Float16)uB01
                      + a10.h * (_Float16)uB10 + a11.h * (_Float16)uB11;
            rrB = rrB * (_Float16)avB;
            *(half8*)&Ald[group][(s + 1) & 1][px][32 + cq * 8] = rrB;
        }
        // (2) coords(s+2) + issue gathers(s+2) + d(s+3)
        if (s < 16) {
            int tA = gs0 + 2 * (s + 2), tB = tA + 1;
            int i00;
            calc_coords(h, px, (tA % 9) / 3, (tA % 9) % 3, dyA, dxA, i00,
                        uA00, uA01, uA10, uA11);
            const _Float16* xga = xbase + (tA / 9) * 32 + (long)i00 * 256;
            qa0 = *(const uint4*)(xga);
            qa1 = *(const uint4*)(xga + 256);
            qa2 = *(const uint4*)(xga + XROW);
            qa3 = *(const uint4*)(xga + XROW + 256);
            calc_coords(h, px, (tB % 9) / 3, (tB % 9) % 3, dyB, dxB, i00,
                        uB00, uB01, uB10, uB11);
            const _Float16* xgb = xbase + (tB / 9) * 32 + (long)i00 * 256;
            qb0 = *(const uint4*)(xgb);
            qb1 = *(const uint4*)(xgb + 256);
            qb2 = *(const uint4*)(xgb + XROW);
            qb3 = *(const uint4*)(xgb + XROW + 256);
            int s3 = min(s + 3, 17);
            int t3 = gs0 + 2 * s3;
            dyA = cbase[(2 * t3) * HW + px];     dxA = cbase[(2 * t3 + 1) * HW + px];
            dyB = cbase[(2 * t3 + 2) * HW + px]; dxB = cbase[(2 * t3 + 3) * HW + px];
        }
        // (3) MFMA(s): 2 K-halves x 4 M x 4 N
        {
            const int k0 = (lane >> 4) * 8;
            U4H8 b0, b1, b2, b3;
            b0.u = ba0; b1.u = ba1; b2.u = ba2; b3.u = ba3;
            #pragma unroll
            for (int mi = 0; mi < 4; ++mi) {
                half8 a = *(const half8*)&Ald[group][s & 1][mi * 16 + (lane & 15)][k0];
                acc[mi][0] = __builtin_amdgcn_mfma_f32_16x16x32_f16(a, b0.h, acc[mi][0], 0, 0, 0);
                acc[mi][1] = __builtin_amdgcn_mfma_f32_16x16x32_f16(a, b1.h, acc[mi][1], 0, 0, 0);
                acc[mi][2] = __builtin_amdgcn_mfma_f32_16x16x32_f16(a, b2.h, acc[mi][2], 0, 0, 0);
                acc[mi][3] = __builtin_amdgcn_mfma_f32_16x16x32_f16(a, b3.h, acc[mi][3], 0, 0, 0);
            }
            b0.u = bb0; b1.u = bb1; b2.u = bb2; b3.u = bb3;
            #pragma unroll
            for (int mi = 0; mi < 4; ++mi) {
                half8 a = *(const half8*)&Ald[group][s & 1][mi * 16 + (lane & 15)][32 + k0];
                acc[mi][0] = __builtin_amdgcn_mfma_f32_16x16x32_f16(a, b0.h, acc[mi][0], 0, 0, 0);
                acc[mi][1] = __builtin_amdgcn_mfma_f32_16x16x32_f16(a, b1.h, acc[mi][1], 0, 0, 0);
                acc[mi][2] = __builtin_amdgcn_mfma_f32_16x16x32_f16(a, b2.h, acc[mi][2], 0, 0, 0);
                acc[mi][3] = __builtin_amdgcn_mfma_f32_16x16x32_f16(a, b3.h, acc[mi][3], 0, 0, 0);
            }
        }
        // (4) issue B(s+1) pair
        if (s < 17) {
            int gs = gs0 + 2 * (s + 1);
            const _Float16* wa = wB3 + (long)gs * 8192;
            ba0 = *(const uint4*)(wa);
            ba1 = *(const uint4*)(wa + 512);
            ba2 = *(const uint4*)(wa + 1024);
            ba3 = *(const uint4*)(wa + 1536);
            const _Float16* wb_ = wB3 + (long)(gs + 1) * 8192;
            bb0 = *(const uint4*)(wb_);
            bb1 = *(const uint4*)(wb_ + 512);
            bb2 = *(const uint4*)(wb_ + 1024);
            bb3 = *(const uint4*)(wb_ + 1536);
        }
        // (5) LDS-visibility barrier only
        LGKM0_BARRIER();
    }

    // ---- cross-group K reduction via LDS (2 rounds) ----
    #pragma unroll
    for (int r = 0; r < 2; ++r) {
        __syncthreads();
        if (group == 1) {
            #pragma unroll
            for (int m2 = 0; m2 < 2; ++m2)
                #pragma unroll
                for (int j = 0; j < 4; ++j)
                    *(f32x4*)&red[tl * 36 + m2 * 16 + j * 4] = acc[r * 2 + m2][j];
        }
        __syncthreads();
        if (group == 0) {
            #pragma unroll
            for (int m2 = 0; m2 < 2; ++m2)
                #pragma unroll
                for (int j = 0; j < 4; ++j) {
                    f32x4 v = *(const f32x4*)&red[tl * 36 + m2 * 16 + j * 4];
                    acc[r * 2 + m2][j] += v;
                }
        }
    }

    // ---- epilogue (group 0 stores) ----
    if (group == 0) {
        const int colb = (lane >> 4) * 4;
        #pragma unroll
        for (int mi = 0; mi < 4; ++mi) {
            int px0 = mi * 16 + colb;
            #pragma unroll
            for (int j = 0; j < 4; ++j) {
                int oc = wg * 64 + j * 16 + (lane & 15);
                float bb = b_out[oc];
                float4 v = make_float4(acc[mi][j][0] + bb, acc[mi][j][1] + bb,
                                       acc[mi][j][2] + bb, acc[mi][j][3] + bb);
                *(float4*)&out[((long)b * OO + oc) * HW + h * WW + px0] = v;
            }
        }
    }
}

// ---------------------------------------------------------------------------
extern "C" void kernel_launch(void* const* d_in, const int* in_sizes, int n_in,
                              void* d_out, int out_size, void* d_ws, size_t ws_size,
                              hipStream_t stream) {
    const float* x      = (const float*)d_in[0];
    const float* w_off  = (const float*)d_in[1];
    const float* b_off  = (const float*)d_in[2];
    const float* w_attn = (const float*)d_in[3];
    const float* b_attn = (const float*)d_in[4];
    const float* w_out  = (const float*)d_in[5];
    const float* b_out  = (const float*)d_in[6];
    float* out = (float*)d_out;

    _Float16* x_h     = (_Float16*)d_ws;                    // 8*68*68*256 = 9,469,952 halves
    float* conv_buf   = (float*)(x_h + 9469952);            // 7,077,888 floats
    _Float16* wt3     = (_Float16*)(conv_buf + 7077888);    // 589,824 halves
    _Float16* wt_conv = wt3 + 589824;                       // 589,824 halves
    float* bias_c     = (float*)(wt_conv + 589824);         // 224 floats

    // zero the halo'd x_h once; repack writes the interior
    hipMemsetAsync(x_h, 0, (size_t)9469952 * sizeof(_Float16), stream);

    repack_w<<<dim3((589824 + 255) / 256), dim3(256), 0, stream>>>(w_out, wt3);
    repack_conv<<<dim3((9 * NPAD * 256 + 255) / 256), dim3(256), 0, stream>>>(
        w_off, b_off, w_attn, b_attn, wt_conv, bias_c);
    repack_x<<<dim3(512), dim3(256), 0, stream>>>(x, x_h);

    conv_mfma<<<dim3(512), dim3(512), 0, stream>>>(x_h, wt_conv, bias_c, conv_buf);

    sample_gemm_mfma<<<dim3(512), dim3(512), 0, stream>>>(
        x_h, conv_buf, wt3, b_out, out);
}

// Round 14
// 201.393 us; speedup vs baseline: 1.2230x; 1.0678x over previous
//
#include <hip/hip_runtime.h>

// Problem constants
#define BN   8
#define CC   256
#define HH   64
#define WW   64
#define GG   8
#define CG   32
#define KKK  9
#define OO   256
#define HW   (HH*WW)
#define NPAD 256
#define NOUT 216

// halo'd x_h geometry: pixel (y,x) lives at row y+2, col x+2 of a 68x68 grid
#define XH   68
#define XROW (XH*256)            // halves per pixel-row = 17408
#define XB   (XH*XH*256)         // halves per batch    = 1183744

typedef __attribute__((ext_vector_type(8))) _Float16 half8;
typedef __attribute__((ext_vector_type(4))) float f32x4;

union U4H8 { uint4 u; half8 h; };

#define LGKM0_BARRIER() do { \
    asm volatile("s_waitcnt lgkmcnt(0)" ::: "memory"); \
    __builtin_amdgcn_s_barrier(); \
    __builtin_amdgcn_sched_barrier(0); \
} while (0)

// ---------------------------------------------------------------------------
// prep_all: ONE launch doing all preprocessing.
//  blocks [0,512)        : repack_x  f32 NCHW -> x_h f16 halo-NHWC (interior)
//  blocks [512,2816)     : repack_w  -> wt3 fragment-linear
//  blocks [2816,5120)    : repack_conv -> wt_conv fragment-linear + bias
//  blocks [5120,5648)    : zero the 528-cell halo border of x_h per batch
// Disjoint outputs (interior vs halo; separate buffers) -> no ordering hazard.
// ---------------------------------------------------------------------------
__global__ __launch_bounds__(256) void prep_all(
    const float* __restrict__ x, const float* __restrict__ w_out,
    const float* __restrict__ w_off, const float* __restrict__ b_off,
    const float* __restrict__ w_attn, const float* __restrict__ b_attn,
    _Float16* __restrict__ x_h, _Float16* __restrict__ wt3,
    _Float16* __restrict__ wt_conv, float* __restrict__ bias_c) {
    const int bid = blockIdx.x;
    const int t = threadIdx.x;

    if (bid < 512) {
        // ---- repack_x (interior) ----
        __shared__ _Float16 T[64][264];
        const int b = bid & 7, h = bid >> 3;
        const float* src = x + (((long)(b * 256 + t)) << 12) + h * 64;
        #pragma unroll
        for (int i = 0; i < 16; ++i) {
            float4 f = ((const float4*)src)[i];
            T[i * 4 + 0][t] = (_Float16)f.x;
            T[i * 4 + 1][t] = (_Float16)f.y;
            T[i * 4 + 2][t] = (_Float16)f.z;
            T[i * 4 + 3][t] = (_Float16)f.w;
        }
        __syncthreads();
        _Float16* dst = x_h + ((long)(b * XH + h + 2) * XH + 2) * 256;
        #pragma unroll
        for (int it = 0; it < 8; ++it) {
            int idx = it * 256 + t;
            int px = idx >> 5, ch = idx & 31;
            uint4 v = *(const uint4*)&T[px][ch * 8];
            *(uint4*)(dst + px * 256 + ch * 8) = v;
        }
    } else if (bid < 2816) {
        // ---- repack_w ----
        int idx = (bid - 512) * 256 + t;          // < 589,824 exactly
        int e    = idx & 7;
        int lane = (idx >> 3) & 63;
        int ot   = (idx >> 9) & 15;
        int s    = idx >> 13;                     // 0..71
        int kk = s % 9;
        int g  = s / 9;
        int oc = ot * 16 + (lane & 15);
        int cg = (lane >> 4) * 8 + e;
        wt3[idx] = (_Float16)w_out[oc * 2304 + (g * 32 + cg) * 9 + kk];
    } else if (bid < 5120) {
        // ---- repack_conv ----
        int idx = (bid - 2816) * 256 + t;         // < 589,824 exactly
        int e    = idx & 7;
        int lane = (idx >> 3) & 63;
        int ot   = (idx >> 9) & 15;
        int gs   = idx >> 13;                     // 0..71
        int tap = gs >> 3;
        int ch  = (gs & 7) * 32 + (lane >> 4) * 8 + e;
        int n   = ot * 16 + (lane & 15);
        float v = 0.f;
        if (n < 144)      v = w_off[(n * 256 + ch) * 9 + tap];
        else if (n < 216) v = w_attn[((n - 144) * 256 + ch) * 9 + tap];
        wt_conv[idx] = (_Float16)v;
        if (idx < 224) {
            float bv = 0.f;
            if (idx < 144)      bv = b_off[idx];
            else if (idx < 216) bv = b_attn[idx - 144];
            bias_c[idx] = bv;
        }
    } else {
        // ---- halo zero: 528 border cells/batch x 32 uint4/cell x 8 batches ----
        int gi = (bid - 5120) * 256 + t;          // < 135,168 exactly
        int b    = gi / 16896;
        int r    = gi - b * 16896;
        int cell = r >> 5;                        // 0..527
        int q    = r & 31;                        // uint4 within cell
        int row, col;
        if (cell < 272) {                         // 4 border rows x 68 cols
            int rr = cell / 68;
            row = (rr < 2) ? rr : (rr + 64);      // 0,1,66,67
            col = cell - rr * 68;
        } else {                                  // 64 rows x 4 border cols
            int cc = cell - 272;
            row = 2 + (cc >> 2);
            int ci = cc & 3;
            col = (ci < 2) ? ci : (ci + 64);      // 0,1,66,67
        }
        _Float16* p = x_h + ((long)(b * XH + row) * XH + col) * 256 + q * 8;
        *(uint4*)p = make_uint4(0u, 0u, 0u, 0u);
    }
}

// ---------------------------------------------------------------------------
// K1: implicit-GEMM conv via f16 MFMA, split-K, BK=64 (2 chunks per stage).
// Block = 512 thr (8 waves) = 2 K-groups x 4 N-waves. M=64 px, N=256 (padded).
// Grid 512 = (b,h). 18 stages/group, 32 MFMA/wave/stage, ONE lgkm-only
// barrier per stage. (R10 kernel, verified.)
// ---------------------------------------------------------------------------
__global__ __launch_bounds__(512, 4) void conv_mfma(
    const _Float16* __restrict__ x_h, const _Float16* __restrict__ wt_conv,
    const float* __restrict__ bias_c, float* __restrict__ conv_buf) {
    __shared__ alignas(16) char smem[36864];
    _Float16 (*Ald)[2][64][72] = (_Float16 (*)[2][64][72])smem; // 36,864 B
    float* red = (float*)smem;                                  // epilogue reuse

    const int bid = blockIdx.x;
    const int b = bid & 7, h = bid >> 3;
    const int t = threadIdx.x;
    const int lane = t & 63;
    const int wv = t >> 6;
    const int group = wv >> 2;      // K-half: gs 0..35 | 36..71
    const int wg = wv & 3;          // N quarter
    const int tl = t & 255;
    const int px = tl >> 2, cq = tl & 3;
    const int gs0 = group * 36;

    f32x4 acc[4][4];
    #pragma unroll
    for (int i = 0; i < 4; ++i)
        #pragma unroll
        for (int j = 0; j < 4; ++j) acc[i][j] = (f32x4){0.f, 0.f, 0.f, 0.f};

    const _Float16* xb = x_h + (long)b * XB + cq * 8;
    const _Float16* wB = wt_conv + (long)(wg * 256 + lane) * 8;

    uint4 aR0, aR1;
    uint4 ba0, ba1, ba2, ba3;   // B even slice (kh=0)
    uint4 bb0, bb1, bb2, bb3;   // B odd slice  (kh=1)

    // ---- prologue: A(0) -> buf0; A(1) -> regs; B(0) pair -> regs ----
    {
        int gs = gs0;
        int tap = gs >> 3, cb = (gs & 7) * 32;
        int y = h + tap / 3 + 1, xc = px + tap % 3 + 1;
        const _Float16* p = xb + ((long)(y * XH + xc)) * 256 + cb;
        uint4 a0 = *(const uint4*)(p);
        uint4 a1 = *(const uint4*)(p + 32);
        *(uint4*)&Ald[group][0][px][cq * 8] = a0;
        *(uint4*)&Ald[group][0][px][32 + cq * 8] = a1;
    }
    {
        int gs = gs0 + 2;
        int tap = gs >> 3, cb = (gs & 7) * 32;
        int y = h + tap / 3 + 1, xc = px + tap % 3 + 1;
        const _Float16* p = xb + ((long)(y * XH + xc)) * 256 + cb;
        aR0 = *(const uint4*)(p);
        aR1 = *(const uint4*)(p + 32);
    }
    {
        const _Float16* wa = wB + (long)gs0 * 8192;
        ba0 = *(const uint4*)(wa);
        ba1 = *(const uint4*)(wa + 512);
        ba2 = *(const uint4*)(wa + 1024);
        ba3 = *(const uint4*)(wa + 1536);
        const _Float16* wb_ = wB + (long)(gs0 + 1) * 8192;
        bb0 = *(const uint4*)(wb_);
        bb1 = *(const uint4*)(wb_ + 512);
        bb2 = *(const uint4*)(wb_ + 1024);
        bb3 = *(const uint4*)(wb_ + 1536);
    }
    LGKM0_BARRIER();

    for (int s = 0; s < 18; ++s) {
        // (1) LDS write A(s+1) from prefetched regs (other buffer)
        if (s < 17) {
            *(uint4*)&Ald[group][(s + 1) & 1][px][cq * 8] = aR0;
            *(uint4*)&Ald[group][(s + 1) & 1][px][32 + cq * 8] = aR1;
        }
        // (2) issue A(s+2)
        if (s < 16) {
            int gs = gs0 + 2 * (s + 2);
            int tap = gs >> 3, cb = (gs & 7) * 32;
            int y = h + tap / 3 + 1, xc = px + tap % 3 + 1;
            const _Float16* p = xb + ((long)(y * XH + xc)) * 256 + cb;
            aR0 = *(const uint4*)(p);
            aR1 = *(const uint4*)(p + 32);
        }
        // (3) MFMA(s): 2 K-halves x 4 M x 4 N from LDS buf[s&1]
        {
            const int k0 = (lane >> 4) * 8;
            U4H8 b0, b1, b2, b3;
            b0.u = ba0; b1.u = ba1; b2.u = ba2; b3.u = ba3;
            #pragma unroll
            for (int mi = 0; mi < 4; ++mi) {
                half8 a = *(const half8*)&Ald[group][s & 1][mi * 16 + (lane & 15)][k0];
                acc[mi][0] = __builtin_amdgcn_mfma_f32_16x16x32_f16(a, b0.h, acc[mi][0], 0, 0, 0);
                acc[mi][1] = __builtin_amdgcn_mfma_f32_16x16x32_f16(a, b1.h, acc[mi][1], 0, 0, 0);
                acc[mi][2] = __builtin_amdgcn_mfma_f32_16x16x32_f16(a, b2.h, acc[mi][2], 0, 0, 0);
                acc[mi][3] = __builtin_amdgcn_mfma_f32_16x16x32_f16(a, b3.h, acc[mi][3], 0, 0, 0);
            }
            b0.u = bb0; b1.u = bb1; b2.u = bb2; b3.u = bb3;
            #pragma unroll
            for (int mi = 0; mi < 4; ++mi) {
                half8 a = *(const half8*)&Ald[group][s & 1][mi * 16 + (lane & 15)][32 + k0];
                acc[mi][0] = __builtin_amdgcn_mfma_f32_16x16x32_f16(a, b0.h, acc[mi][0], 0, 0, 0);
                acc[mi][1] = __builtin_amdgcn_mfma_f32_16x16x32_f16(a, b1.h, acc[mi][1], 0, 0, 0);
                acc[mi][2] = __builtin_amdgcn_mfma_f32_16x16x32_f16(a, b2.h, acc[mi][2], 0, 0, 0);
                acc[mi][3] = __builtin_amdgcn_mfma_f32_16x16x32_f16(a, b3.h, acc[mi][3], 0, 0, 0);
            }
        }
        // (4) issue B(s+1) pair
        if (s < 17) {
            int gs = gs0 + 2 * (s + 1);
            const _Float16* wa = wB + (long)gs * 8192;
            ba0 = *(const uint4*)(wa);
            ba1 = *(const uint4*)(wa + 512);
            ba2 = *(const uint4*)(wa + 1024);
            ba3 = *(const uint4*)(wa + 1536);
            const _Float16* wb_ = wB + (long)(gs + 1) * 8192;
            bb0 = *(const uint4*)(wb_);
            bb1 = *(const uint4*)(wb_ + 512);
            bb2 = *(const uint4*)(wb_ + 1024);
            bb3 = *(const uint4*)(wb_ + 1536);
        }
        // (5) LDS-visibility barrier only (no vmcnt drain)
        LGKM0_BARRIER();
    }

    // ---- cross-group K reduction via LDS (2 rounds) ----
    #pragma unroll
    for (int r = 0; r < 2; ++r) {
        __syncthreads();
        if (group == 1) {
            #pragma unroll
            for (int m2 = 0; m2 < 2; ++m2)
                #pragma unroll
                for (int j = 0; j < 4; ++j)
                    *(f32x4*)&red[tl * 36 + m2 * 16 + j * 4] = acc[r * 2 + m2][j];
        }
        __syncthreads();
        if (group == 0) {
            #pragma unroll
            for (int m2 = 0; m2 < 2; ++m2)
                #pragma unroll
                for (int j = 0; j < 4; ++j) {
                    f32x4 v = *(const f32x4*)&red[tl * 36 + m2 * 16 + j * 4];
                    acc[r * 2 + m2][j] += v;
                }
        }
    }

    // ---- epilogue (group 0 stores) ----
    if (group == 0) {
        const int colb = (lane >> 4) * 4;
        #pragma unroll
        for (int mi = 0; mi < 4; ++mi) {
            int px0 = mi * 16 + colb;
            #pragma unroll
            for (int j = 0; j < 4; ++j) {
                int oc = wg * 64 + j * 16 + (lane & 15);
                if (oc < NOUT) {
                    float bb = bias_c[oc];
                    float4 v = make_float4(acc[mi][j][0] + bb, acc[mi][j][1] + bb,
                                           acc[mi][j][2] + bb, acc[mi][j][3] + bb);
                    *(float4*)&conv_buf[((long)b * NOUT + oc) * HW + h * WW + px0] = v;
                }
            }
        }
    }
}

// ---------------------------------------------------------------------------
// coords on the zero-halo grid: NO masks, NO per-corner selects.
// ---------------------------------------------------------------------------
__device__ __forceinline__ void calc_coords(int h, int px, int ki, int kj,
    float dy, float dx, int& i00,
    float& u00, float& u01, float& u10, float& u11) {
    float py  = (float)(h - 1 + ki) + dy;
    float pxf = (float)(px - 1 + kj) + dx;
    float y0f = floorf(py), x0f = floorf(pxf);
    float wy1 = py - y0f, wx1 = pxf - x0f;
    float wy0 = 1.f - wy1, wx0 = 1.f - wx1;
    int y0 = min(max((int)y0f, -2), 64);
    int x0 = min(max((int)x0f, -2), 64);
    u00 = wy0 * wx0; u01 = wy0 * wx1;
    u10 = wy1 * wx0; u11 = wy1 * wx1;
    i00 = (y0 + 2) * XH + (x0 + 2);
}

// ---------------------------------------------------------------------------
// K3: fused softmax + bilinear sampling + modulation + MFMA contraction.
// Split-K, BK=32, 36 stages, one lgkm-only barrier per stage. Zero-halo
// gathers; fragment-linear B. (R8/R10 kernel, verified 70.6 us.)
// ---------------------------------------------------------------------------
__global__ __launch_bounds__(512, 4) void sample_gemm_mfma(
    const _Float16* __restrict__ x_h, const float* __restrict__ conv_buf,
    const _Float16* __restrict__ wt3,
    const float* __restrict__ b_out, float* __restrict__ out) {
    __shared__ alignas(16) char smem[38912];
    _Float16 (*Ald)[2][64][40] = (_Float16 (*)[2][64][40])smem; // 20,480 B
    float* attnL = (float*)(smem + 20480);                      // 18,432 B
    float* red = (float*)smem;                                  // epilogue reuse

    const int bid = blockIdx.x;
    const int b = bid & 7, h = bid >> 3;
    const int t = threadIdx.x;
    const int lane = t & 63;
    const int wv = t >> 6;
    const int group = wv >> 2;      // K-half
    const int wg = wv & 3;          // N quarter
    const int tl = t & 255;
    const int px = tl >> 2, cq = tl & 3;
    const int gs0 = group * 36;

    f32x4 acc[4][4];
    #pragma unroll
    for (int i = 0; i < 4; ++i)
        #pragma unroll
        for (int j = 0; j < 4; ++j) acc[i][j] = (f32x4){0.f, 0.f, 0.f, 0.f};

    const float* cbase = conv_buf + (long)b * NOUT * HW + h * WW;
    const _Float16* xbase = x_h + (long)b * XB + cq * 8;
    const _Float16* wB3 = wt3 + (long)(wg * 256 + lane) * 8;

    // ---- preamble 1: softmax over 9 taps; 512 threads cover (g, px) ----
    {
        int ppx = t & 63, g = t >> 6;
        const float* ap = cbase + (long)(144 + g * 9) * HW + ppx;
        float v[9];
        float m = -1e30f;
        #pragma unroll
        for (int k = 0; k < 9; ++k) { v[k] = ap[k * HW]; m = fmaxf(m, v[k]); }
        float ssum = 0.f;
        #pragma unroll
        for (int k = 0; k < 9; ++k) { v[k] = __expf(v[k] - m); ssum += v[k]; }
        float inv = 1.f / ssum;
        #pragma unroll
        for (int k = 0; k < 9; ++k) attnL[(g * 9 + k) * 64 + ppx] = v[k] * inv;
    }
    float dy0 = cbase[(2 * gs0) * HW + px], dx0 = cbase[(2 * gs0 + 1) * HW + px];
    __syncthreads();   // attnL ready

    // ---- preamble 2: A(0) -> buf0; prefetch gathers(1), d(2), B(0) ----
    uint4 q00, q01, q10, q11;
    float u00, u01, u10, u11;
    float dyN, dxN;
    uint4 bq0, bq1, bq2, bq3;
    {
        int i00;
        float v00, v01, v10, v11;
        calc_coords(h, px, 0, 0, dy0, dx0, i00, v00, v01, v10, v11);
        const _Float16* xg = xbase + (group * 4) * 32 + (long)i00 * 256;
        uint4 a00 = *(const uint4*)(xg);
        uint4 a01 = *(const uint4*)(xg + 256);
        uint4 a10 = *(const uint4*)(xg + XROW);
        uint4 a11 = *(const uint4*)(xg + XROW + 256);
        float av = attnL[gs0 * 64 + px];
        U4H8 h00, h01, h10, h11;
        h00.u = a00; h01.u = a01; h10.u = a10; h11.u = a11;
        half8 rr = h00.h * (_Float16)v00 + h01.h * (_Float16)v01
                 + h10.h * (_Float16)v10 + h11.h * (_Float16)v11;
        rr = rr * (_Float16)av;
        *(half8*)&Ald[group][0][px][cq * 8] = rr;
    }
    {
        // gathers for stage 1 (kk=1, same g)
        float dy1 = cbase[(2 * (gs0 + 1)) * HW + px];
        float dx1 = cbase[(2 * (gs0 + 1) + 1) * HW + px];
        int i00;
        calc_coords(h, px, 0, 1, dy1, dx1, i00, u00, u01, u10, u11);
        const _Float16* xg = xbase + (group * 4) * 32 + (long)i00 * 256;
        q00 = *(const uint4*)(xg);
        q01 = *(const uint4*)(xg + 256);
        q10 = *(const uint4*)(xg + XROW);
        q11 = *(const uint4*)(xg + XROW + 256);
        dyN = cbase[(2 * (gs0 + 2)) * HW + px];
        dxN = cbase[(2 * (gs0 + 2) + 1) * HW + px];
    }
    {
        const _Float16* wsB = wB3 + (long)gs0 * 8192;
        bq0 = *(const uint4*)(wsB);
        bq1 = *(const uint4*)(wsB + 512);
        bq2 = *(const uint4*)(wsB + 1024);
        bq3 = *(const uint4*)(wsB + 1536);
    }
    LGKM0_BARRIER();

    for (int s = 0; s < 36; ++s) {
        const int gs = gs0 + s;
        // (1) blend A(s+1) from prefetched gathers; LDS write (other buffer)
        if (s < 35) {
            float av = attnL[(gs + 1) * 64 + px];
            U4H8 a00, a01, a10, a11;
            a00.u = q00; a01.u = q01; a10.u = q10; a11.u = q11;
            half8 rr = a00.h * (_Float16)u00 + a01.h * (_Float16)u01
                     + a10.h * (_Float16)u10 + a11.h * (_Float16)u11;
            rr = rr * (_Float16)av;
            *(half8*)&Ald[group][(s + 1) & 1][px][cq * 8] = rr;
        }
        // (2) coords(s+2) + issue gathers(s+2) + d(s+3)
        if (s < 34) {
            int sn = s + 2;
            int g = group * 4 + sn / 9, kk = sn % 9;
            int i00;
            calc_coords(h, px, kk / 3, kk % 3, dyN, dxN, i00, u00, u01, u10, u11);
            const _Float16* xg = xbase + g * 32 + (long)i00 * 256;
            q00 = *(const uint4*)(xg);
            q01 = *(const uint4*)(xg + 256);
            q10 = *(const uint4*)(xg + XROW);
            q11 = *(const uint4*)(xg + XROW + 256);
            int s3 = min(s + 3, 35);
            dyN = cbase[(2 * (gs0 + s3)) * HW + px];
            dxN = cbase[(2 * (gs0 + s3) + 1) * HW + px];
        }
        // (3) MFMA(s)
        {
            const int k0 = (lane >> 4) * 8;
            U4H8 b0, b1, b2, b3; b0.u = bq0; b1.u = bq1; b2.u = bq2; b3.u = bq3;
            #pragma unroll
            for (int mi = 0; mi < 4; ++mi) {
                half8 a = *(const half8*)&Ald[group][s & 1][mi * 16 + (lane & 15)][k0];
                acc[mi][0] = __builtin_amdgcn_mfma_f32_16x16x32_f16(a, b0.h, acc[mi][0], 0, 0, 0);
                acc[mi][1] = __builtin_amdgcn_mfma_f32_16x16x32_f16(a, b1.h, acc[mi][1], 0, 0, 0);
                acc[mi][2] = __builtin_amdgcn_mfma_f32_16x16x32_f16(a, b2.h, acc[mi][2], 0, 0, 0);
                acc[mi][3] = __builtin_amdgcn_mfma_f32_16x16x32_f16(a, b3.h, acc[mi][3], 0, 0, 0);
            }
        }
        // (4) issue B(s+1)
        if (s < 35) {
            const _Float16* wsB = wB3 + (long)(gs + 1) * 8192;
            bq0 = *(const uint4*)(wsB);
            bq1 = *(const uint4*)(wsB + 512);
            bq2 = *(const uint4*)(wsB + 1024);
            bq3 = *(const uint4*)(wsB + 1536);
        }
        // (5) LDS-visibility barrier only
        LGKM0_BARRIER();
    }

    // ---- cross-group K reduction via LDS (2 rounds) ----
    #pragma unroll
    for (int r = 0; r < 2; ++r) {
        __syncthreads();
        if (group == 1) {
            #pragma unroll
            for (int m2 = 0; m2 < 2; ++m2)
                #pragma unroll
                for (int j = 0; j < 4; ++j)
                    *(f32x4*)&red[tl * 36 + m2 * 16 + j * 4] = acc[r * 2 + m2][j];
        }
        __syncthreads();
        if (group == 0) {
            #pragma unroll
            for (int m2 = 0; m2 < 2; ++m2)
                #pragma unroll
                for (int j = 0; j < 4; ++j) {
                    f32x4 v = *(const f32x4*)&red[tl * 36 + m2 * 16 + j * 4];
                    acc[r * 2 + m2][j] += v;
                }
        }
    }

    // ---- epilogue (group 0 stores) ----
    if (group == 0) {
        const int colb = (lane >> 4) * 4;
        #pragma unroll
        for (int mi = 0; mi < 4; ++mi) {
            int px0 = mi * 16 + colb;
            #pragma unroll
            for (int j = 0; j < 4; ++j) {
                int oc = wg * 64 + j * 16 + (lane & 15);
                float bb = b_out[oc];
                float4 v = make_float4(acc[mi][j][0] + bb, acc[mi][j][1] + bb,
                                       acc[mi][j][2] + bb, acc[mi][j][3] + bb);
                *(float4*)&out[((long)b * OO + oc) * HW + h * WW + px0] = v;
            }
        }
    }
}

// ---------------------------------------------------------------------------
extern "C" void kernel_launch(void* const* d_in, const int* in_sizes, int n_in,
                              void* d_out, int out_size, void* d_ws, size_t ws_size,
                              hipStream_t stream) {
    const float* x      = (const float*)d_in[0];
    const float* w_off  = (const float*)d_in[1];
    const float* b_off  = (const float*)d_in[2];
    const float* w_attn = (const float*)d_in[3];
    const float* b_attn = (const float*)d_in[4];
    const float* w_out  = (const float*)d_in[5];
    const float* b_out  = (const float*)d_in[6];
    float* out = (float*)d_out;

    _Float16* x_h     = (_Float16*)d_ws;                    // 8*68*68*256 = 9,469,952 halves
    float* conv_buf   = (float*)(x_h + 9469952);            // 7,077,888 floats
    _Float16* wt3     = (_Float16*)(conv_buf + 7077888);    // 589,824 halves
    _Float16* wt_conv = wt3 + 589824;                       // 589,824 halves
    float* bias_c     = (float*)(wt_conv + 589824);         // 224 floats

    // one merged prep launch: repack_x + repack_w + repack_conv + halo-zero
    prep_all<<<dim3(5648), dim3(256), 0, stream>>>(
        x, w_out, w_off, b_off, w_attn, b_attn, x_h, wt3, wt_conv, bias_c);

    conv_mfma<<<dim3(512), dim3(512), 0, stream>>>(x_h, wt_conv, bias_c, conv_buf);

    sample_gemm_mfma<<<dim3(512), dim3(512), 0, stream>>>(
        x_h, conv_buf, wt3, b_out, out);
}